// Round 17
// baseline (327.730 us; speedup 1.0000x reference)
//
#include <hip/hip_runtime.h>
#include <hip/hip_bf16.h>
#include <stdint.h>

#define DI __device__ __forceinline__

namespace {

constexpr int BB  = 256;   // batch
constexpr int LL  = 128;   // seq len
constexpr int DM  = 64;    // d_model
constexpr int DFF = 512;   // ffn dim
constexpr int NL  = 6;     // layers
constexpr int TT  = BB * LL;  // 32768 tokens

typedef __attribute__((ext_vector_type(8))) short bf16x8;   // MFMA A/B frag (4 VGPR)
typedef __attribute__((ext_vector_type(4))) float f32x4;    // MFMA C/D frag

// ---------- bf16 helpers ----------
DI float bf2f(uint16_t u) { union { uint32_t i; float f; } w; w.i = (uint32_t)u << 16; return w.f; }
DI uint16_t f2bf(float f) {
  union { float f; uint32_t i; } w; w.f = f;
  uint32_t r = (w.i + 0x7fffu + ((w.i >> 16) & 1u)) >> 16;  // RNE
  return (uint16_t)r;
}
DI uint32_t pack2(float a, float b) { return (uint32_t)f2bf(a) | ((uint32_t)f2bf(b) << 16); }

// fragment load: lane l reads 8 bf16 at row (l&15), k-offset (l>>4)*8 of a row-major [16 x ld] tile
DI bf16x8 fragld(const uint16_t* __restrict__ base, int ld, int lane) {
  return *(const bf16x8*)(base + (size_t)(lane & 15) * ld + (lane >> 4) * 8);
}
DI f32x4 MFMA(bf16x8 a, bf16x8 b, f32x4 c) {
  return __builtin_amdgcn_mfma_f32_16x16x32_bf16(a, b, c, 0, 0, 0);
}

// ---------- setup kernels ----------
__global__ void __launch_bounds__(256) k_embed(const int* __restrict__ enc, const int* __restrict__ deg,
    const float* __restrict__ semb, const float* __restrict__ demb,
    float* __restrict__ x, uint16_t* __restrict__ xb) {
  int idx = blockIdx.x * 256 + threadIdx.x;   // T*64
  int t = idx >> 6, d = idx & 63;
  int l = t & (LL - 1);
  float e = (float)(d & ~1) * -0.14391156831212787f;   // -ln(10000)/64
  float ang = (float)l * __expf(e);
  float pe = (d & 1) ? __cosf(ang) : __sinf(ang);
  float v = semb[enc[t] * DM + d] + demb[deg[t] * DM + d] + pe;
  x[idx] = v;
  xb[idx] = f2bf(v);
}

__global__ void __launch_bounds__(256) k_trans(const float* __restrict__ w, uint16_t* __restrict__ wt,
    int K, int O, int dstStride, int colOff) {
  int idx = blockIdx.x * 256 + threadIdx.x;   // nmat*K*O
  int KO = K * O;
  int mat = idx / KO;
  int rem = idx - mat * KO;
  int c = rem / K;
  int k = rem - c * K;
  wt[(size_t)mat * dstStride + (size_t)(colOff + c) * K + k] = f2bf(w[((size_t)mat * K + k) * O + c]);
}

// biasT[b][h][r][kk] bf16 = mask(kk) ? -1e9 : md_emb[MD[b,r,kk]][h]   (layer-invariant)
__global__ void __launch_bounds__(256) k_bias2(const int* __restrict__ MD, const float* __restrict__ memb,
    const int* __restrict__ enc, uint16_t* __restrict__ biasT) {
  int o = blockIdx.x * 256 + threadIdx.x;   // BB*LL*LL
  int b  = o >> 14;
  int r  = (o >> 7) & (LL - 1);
  int kk = o & (LL - 1);
  bool mask = (enc[b * LL + kk] == 0);
  int md = MD[o];
  float4 m = *(const float4*)(memb + md * 4);
  float mv[4] = {m.x, m.y, m.z, m.w};
#pragma unroll
  for (int h = 0; h < 4; ++h) {
    uint16_t v = mask ? (uint16_t)0xce6eu : f2bf(mv[h]);
    biasT[(((size_t)(b * 4 + h) * LL) + r) * LL + kk] = v;
  }
}

// ---------- LN helper: v[j][ct] over one 16-row tile (wave-local) ----------
DI void ln_write(float (&v)[4][4], float (&xfh)[4][4], uint16_t* __restrict__ xls,
                 int r0, int g, int c) {
  float sum[4], sq[4];
#pragma unroll
  for (int j = 0; j < 4; ++j) sum[j] = (v[j][0] + v[j][1]) + (v[j][2] + v[j][3]);
#pragma unroll
  for (int off = 1; off < 16; off <<= 1)
#pragma unroll
    for (int j = 0; j < 4; ++j) sum[j] += __shfl_xor(sum[j], off, 64);
#pragma unroll
  for (int j = 0; j < 4; ++j) {
    float mu = sum[j] * 0.015625f;
#pragma unroll
    for (int ct = 0; ct < 4; ++ct) v[j][ct] -= mu;
    sq[j] = (v[j][0] * v[j][0] + v[j][1] * v[j][1]) + (v[j][2] * v[j][2] + v[j][3] * v[j][3]);
  }
#pragma unroll
  for (int off = 1; off < 16; off <<= 1)
#pragma unroll
    for (int j = 0; j < 4; ++j) sq[j] += __shfl_xor(sq[j], off, 64);
#pragma unroll
  for (int j = 0; j < 4; ++j) {
    float rstd = rsqrtf(sq[j] * 0.015625f + 1e-5f);
#pragma unroll
    for (int ct = 0; ct < 4; ++ct) {
      float r = v[j][ct] * rstd;
      xfh[ct][j] = r;
      xls[(r0 + g * 4 + j) * 72 + ct * 16 + c] = f2bf(r);
    }
  }
}

// ---------- LDS layout (bytes), 512-thread / 8-wave block ----------
// XLS [128][72] @ 0                       18432  persistent
// KLS(h) @ 18432 + h*5184  [128][20]+64B  20736  (pads read by kf but x0 in MFMA — must be FINITE;
//                                                 zeroed ONCE at start: 0*NaN=NaN, 0*finite=0)
// VTL(h) @ 39168 + h*4352  [16][136]      17408
// HID(w) @ 18432 + w*4480  [16][140]      35840  (FFN phase, aliases KLS+VTL; ends 54272; finite data)
// CTX    @ 56576           [128][68]      17408
// QSC(w) @ 73984 + w*2304  [2][16][36]    18432  (cols>=16 zeroed once, never clobbered)
// PTL(w) @ 92416 + w*8192  two 4KB P tiles 65536
constexpr int OFF_KLS = 18432;
constexpr int OFF_VTL = 39168;
constexpr int OFF_HID = 18432;
constexpr int OFF_CTX = 56576;
constexpr int OFF_QSC = 73984;
constexpr int OFF_PTL = 92416;
constexpr int LDS_TOTAL = 157952;

// ---------- one attention rt-PAIR (2x16 rows interleaved for ILP) ----------
DI void attn_pair(bf16x8 (&bA)[4], bf16x8 (&bB)[4], bool prefetch,
                  const uint16_t* __restrict__ bb, int nrow0,
                  char* ptl0, char* ptl1, uint16_t* qscw,
                  const bf16x8 (&kf)[8], const uint16_t* vtlh,
                  uint2 q0, uint2 q1, uint2& cr0, uint2& cr1,
                  int lane, int g, int c) {
  int rl = lane >> 2, seg = lane & 3;
  int swz = (rl & 7) << 4;
  // commit both bias tiles (loaded earlier) into swizzled P buffers
#pragma unroll
  for (int m = 0; m < 4; ++m) {
    *(bf16x8*)(ptl0 + rl * 256 + ((seg * 64 + m * 16) ^ swz)) = bA[m];
    *(bf16x8*)(ptl1 + rl * 256 + ((seg * 64 + m * 16) ^ swz)) = bB[m];
  }
  // prefetch next pair's bias into the same regs (T14: latency hides under compute)
  if (prefetch) {
    const uint16_t* gs0 = bb + (size_t)(nrow0 + rl) * LL + seg * 32;
    const uint16_t* gs1 = gs0 + 16 * LL;
#pragma unroll
    for (int m = 0; m < 4; ++m) bA[m] = *(const bf16x8*)(gs0 + m * 8);
#pragma unroll
    for (int m = 0; m < 4; ++m) bB[m] = *(const bf16x8*)(gs1 + m * 8);
  }
  // stage both q C-frags (qsc pads pre-zeroed)
  uint16_t* qs0 = qscw;
  uint16_t* qs1 = qscw + 16 * 36;
  qs0[(g * 4 + 0) * 36 + c] = (uint16_t)(q0.x & 0xffff);
  qs0[(g * 4 + 1) * 36 + c] = (uint16_t)(q0.x >> 16);
  qs0[(g * 4 + 2) * 36 + c] = (uint16_t)(q0.y & 0xffff);
  qs0[(g * 4 + 3) * 36 + c] = (uint16_t)(q0.y >> 16);
  qs1[(g * 4 + 0) * 36 + c] = (uint16_t)(q1.x & 0xffff);
  qs1[(g * 4 + 1) * 36 + c] = (uint16_t)(q1.x >> 16);
  qs1[(g * 4 + 2) * 36 + c] = (uint16_t)(q1.y & 0xffff);
  qs1[(g * 4 + 3) * 36 + c] = (uint16_t)(q1.y >> 16);
  bf16x8 qf0 = fragld(qs0, 36, lane);
  bf16x8 qf1 = fragld(qs1, 36, lane);
  // both QK^T chains interleaved
  f32x4 s0[8], s1[8];
#pragma unroll
  for (int ct = 0; ct < 8; ++ct) {
    s0[ct] = MFMA(qf0, kf[ct], (f32x4){0.f, 0.f, 0.f, 0.f});
    s1[ct] = MFMA(qf1, kf[ct], (f32x4){0.f, 0.f, 0.f, 0.f});
  }
  // both softmax RMW streams interleaved
  float rs0[4] = {0.f, 0.f, 0.f, 0.f}, rs1[4] = {0.f, 0.f, 0.f, 0.f};
#pragma unroll
  for (int ct = 0; ct < 8; ++ct) {
    int kk = ct * 16 + c;
#pragma unroll
    for (int j = 0; j < 4; ++j) {
      int row = g * 4 + j;
      int off = row * 256 + ((kk * 2) ^ ((row & 7) << 4));
      char* a0 = ptl0 + off;
      char* a1 = ptl1 + off;
      float b0 = bf2f(*(uint16_t*)a0);
      float b1 = bf2f(*(uint16_t*)a1);
      float p0 = __expf(fmaf(s0[ct][j], 0.25f, b0));
      float p1 = __expf(fmaf(s1[ct][j], 0.25f, b1));
      rs0[j] += p0;
      rs1[j] += p1;
      *(uint16_t*)a0 = f2bf(p0);
      *(uint16_t*)a1 = f2bf(p1);
    }
  }
#pragma unroll
  for (int off = 1; off < 16; off <<= 1)
#pragma unroll
    for (int j = 0; j < 4; ++j) {
      rs0[j] += __shfl_xor(rs0[j], off, 64);
      rs1[j] += __shfl_xor(rs1[j], off, 64);
    }
  // both PV chains interleaved
  bf16x8 vf[4];
#pragma unroll
  for (int kc = 0; kc < 4; ++kc) vf[kc] = fragld(vtlh + kc * 32, 136, lane);
  f32x4 o0 = {0.f, 0.f, 0.f, 0.f}, o1 = {0.f, 0.f, 0.f, 0.f};
#pragma unroll
  for (int kc = 0; kc < 4; ++kc) {
    int off = c * 256 + ((kc * 64 + g * 16) ^ ((c & 7) << 4));
    o0 = MFMA(*(const bf16x8*)(ptl0 + off), vf[kc], o0);
    o1 = MFMA(*(const bf16x8*)(ptl1 + off), vf[kc], o1);
  }
  cr0.x = pack2(o0[0] / rs0[0], o0[1] / rs0[1]);
  cr0.y = pack2(o0[2] / rs0[2], o0[3] / rs0[3]);
  cr1.x = pack2(o1[0] / rs1[0], o1[1] / rs1[1]);
  cr1.y = pack2(o1[2] / rs1[2], o1[3] / rs1[3]);
}

// ---------- megakernel: one workgroup (512 thr, 8 waves) per b ----------
__global__ void __launch_bounds__(512, 1) k_mega(
    const float* __restrict__ x0, const uint16_t* __restrict__ xb0,
    const uint16_t* __restrict__ biasT,
    const uint16_t* __restrict__ wtqkv, const uint16_t* __restrict__ wto,
    const uint16_t* __restrict__ wt1, const uint16_t* __restrict__ wt2,
    float* __restrict__ out) {
  __shared__ __align__(16) char LDSB[LDS_TOTAL];
  int tid = threadIdx.x;
  int w8 = tid >> 6, lane = tid & 63;
  int g = lane >> 4, c = lane & 15;
  int h = w8 & 3, half = w8 >> 2;      // attn role: head h, rows half*64..+63
  int b = blockIdx.x;

  uint16_t* xls  = (uint16_t*)(LDSB);
  uint16_t* klsh = (uint16_t*)(LDSB + OFF_KLS + h * 5184);
  uint16_t* vtlh = (uint16_t*)(LDSB + OFF_VTL + h * 4352);
  uint16_t* hidl = (uint16_t*)(LDSB + OFF_HID + w8 * 4480);
  uint16_t* ctxl = (uint16_t*)(LDSB + OFF_CTX);
  uint16_t* qscw = (uint16_t*)(LDSB + OFF_QSC + w8 * 2304);
  char*     ptl0 = LDSB + OFF_PTL + w8 * 8192;
  char*     ptl1 = ptl0 + 4096;

  int r0 = w8 * 16;                    // O-proj/FFN rows
  int hrow0 = half * 64;

  // ---- residual regs: rows r0..r0+15, all 64 cols (C-frag layout) ----
  float xf[4][4];
  const float* xrow = x0 + ((size_t)b * LL + r0) * DM;
#pragma unroll
  for (int ct = 0; ct < 4; ++ct)
#pragma unroll
    for (int j = 0; j < 4; ++j)
      xf[ct][j] = xrow[(g * 4 + j) * DM + ct * 16 + c];
  // ---- xls fill (whole b) + qsc zero + ONE-TIME KLS-region zero (NaN guard) ----
  {
    const uint16_t* xbrow = xb0 + (size_t)b * LL * DM;
#pragma unroll
    for (int m = 0; m < 2; ++m) {
      int u = tid * 2 + m;             // 0..1023 units of 8 elems
      int r = u >> 3, col = (u & 7) * 8;
      *(bf16x8*)(xls + r * 72 + col) = *(const bf16x8*)(xbrow + r * DM + col);
    }
#pragma unroll
    for (int m = 0; m < 18; ++m) qscw[lane + m * 64] = 0;
    // zero entire KLS region (incl. pads + tails): uninitialized LDS may hold NaN/Inf
    // bit patterns, and MFMA computes 0*NaN=NaN even though Q's pad k-lanes are zero.
    // After this, every later write into the region (K vals, hid vals) is finite bf16.
    for (int o = tid * 16; o < 20736; o += 512 * 16)
      *(uint4*)(LDSB + OFF_KLS + o) = uint4{0, 0, 0, 0};
  }
  const uint16_t* bb = biasT + ((size_t)b * 4 + h) * (LL * LL);
  __syncthreads();

  for (int li = 0; li < NL; ++li) {
    // ---- QKV: wave (h,half) computes q/k/v of head h for rows hrow0..+63 ----
    const uint16_t* Wl = wtqkv + (size_t)li * 192 * 64;
    bf16x8 bq0 = fragld(Wl + (h * 16) * 64, 64, lane);
    bf16x8 bq1 = fragld(Wl + (h * 16) * 64 + 32, 64, lane);
    bf16x8 bk0 = fragld(Wl + (64 + h * 16) * 64, 64, lane);
    bf16x8 bk1 = fragld(Wl + (64 + h * 16) * 64 + 32, 64, lane);
    bf16x8 bv0 = fragld(Wl + (128 + h * 16) * 64, 64, lane);
    bf16x8 bv1 = fragld(Wl + (128 + h * 16) * 64 + 32, 64, lane);
    uint2 qreg[4];
#pragma unroll
    for (int rt = 0; rt < 4; ++rt) {
      int rr = hrow0 + rt * 16;
      bf16x8 a0 = fragld(xls + rr * 72, 72, lane);
      bf16x8 a1 = fragld(xls + rr * 72 + 32, 72, lane);
      f32x4 aq = {0,0,0,0}, ak = {0,0,0,0}, av = {0,0,0,0};
      aq = MFMA(a0, bq0, aq); aq = MFMA(a1, bq1, aq);
      ak = MFMA(a0, bk0, ak); ak = MFMA(a1, bk1, ak);
      av = MFMA(a0, bv0, av); av = MFMA(a1, bv1, av);
#pragma unroll
      for (int j = 0; j < 4; ++j)
        klsh[(rr + g * 4 + j) * 20 + c] = f2bf(ak[j]);
      uint2 pk; pk.x = pack2(av[0], av[1]); pk.y = pack2(av[2], av[3]);
      *(uint2*)(vtlh + c * 136 + rr + g * 4) = pk;     // V^T [d][kk]
      qreg[rt].x = pack2(aq[0], aq[1]); qreg[rt].y = pack2(aq[2], aq[3]);
    }
    // T14: issue pair-0's bias loads now (complete under barrier + kf loads + QK^T)
    bf16x8 bregA[4], bregB[4];
    {
      int rl = lane >> 2, seg = lane & 3;
      const uint16_t* gs0 = bb + (size_t)(hrow0 + rl) * LL + seg * 32;
      const uint16_t* gs1 = gs0 + 16 * LL;
#pragma unroll
      for (int m = 0; m < 4; ++m) bregA[m] = *(const bf16x8*)(gs0 + m * 8);
#pragma unroll
      for (int m = 0; m < 4; ++m) bregB[m] = *(const bf16x8*)(gs1 + m * 8);
    }
    __syncthreads();   // (1) kls/vtl ready

    // ---- attention: head h, Q rows hrow0..+63, processed as 2 interleaved pairs ----
    bf16x8 kf[8];
#pragma unroll
    for (int ct = 0; ct < 8; ++ct) kf[ct] = fragld(klsh + ct * 16 * 20, 20, lane);
    uint2 creg[4];
    attn_pair(bregA, bregB, true,  bb, hrow0 + 32, ptl0, ptl1, qscw, kf, vtlh,
              qreg[0], qreg[1], creg[0], creg[1], lane, g, c);
    attn_pair(bregA, bregB, false, bb, 0,          ptl0, ptl1, qscw, kf, vtlh,
              qreg[2], qreg[3], creg[2], creg[3], lane, g, c);

    // ---- ctx regs -> ctxl ----
#pragma unroll
    for (int rt = 0; rt < 4; ++rt) {
      int rr = hrow0 + rt * 16;
      ctxl[(rr + g * 4 + 0) * 68 + h * 16 + c] = (uint16_t)(creg[rt].x & 0xffff);
      ctxl[(rr + g * 4 + 1) * 68 + h * 16 + c] = (uint16_t)(creg[rt].x >> 16);
      ctxl[(rr + g * 4 + 2) * 68 + h * 16 + c] = (uint16_t)(creg[rt].y & 0xffff);
      ctxl[(rr + g * 4 + 3) * 68 + h * 16 + c] = (uint16_t)(creg[rt].y >> 16);
    }
    __syncthreads();   // (2) ctxl complete; all kls/vtl reads done (hid may clobber)

    // ---- O-proj + residual + LN (wave owns rows r0..+15) ----
    {
      const uint16_t* Wol = wto + (size_t)li * 64 * 64;
      bf16x8 a0 = fragld(ctxl + r0 * 68, 68, lane);
      bf16x8 a1 = fragld(ctxl + r0 * 68 + 32, 68, lane);
      float v[4][4];
#pragma unroll
      for (int ct = 0; ct < 4; ++ct) {
        f32x4 acc = {0,0,0,0};
        acc = MFMA(a0, fragld(Wol + ct * 16 * 64, 64, lane), acc);
        acc = MFMA(a1, fragld(Wol + ct * 16 * 64 + 32, 64, lane), acc);
#pragma unroll
        for (int j = 0; j < 4; ++j) v[j][ct] = acc[j] + xf[ct][j];
      }
      ln_write(v, xf, xls, r0, g, c);
    }

    // ---- FFN (wave-local rows; hid [16][140], 4 passes of 128 ffn dims) ----
    {
      const uint16_t* W1l = wt1 + (size_t)li * 512 * 64;
      const uint16_t* W2l = wt2 + (size_t)li * 64 * 512;
      bf16x8 a0 = fragld(xls + r0 * 72, 72, lane);
      bf16x8 a1 = fragld(xls + r0 * 72 + 32, 72, lane);
      f32x4 acc2[4] = {{0,0,0,0},{0,0,0,0},{0,0,0,0},{0,0,0,0}};
#pragma unroll
      for (int fh = 0; fh < 4; ++fh) {
#pragma unroll
        for (int ct2 = 0; ct2 < 8; ++ct2) {
          int ctg = fh * 8 + ct2;
          f32x4 acc = {0,0,0,0};
          acc = MFMA(a0, fragld(W1l + ctg * 16 * 64, 64, lane), acc);
          acc = MFMA(a1, fragld(W1l + ctg * 16 * 64 + 32, 64, lane), acc);
#pragma unroll
          for (int j = 0; j < 4; ++j)
            hidl[(g * 4 + j) * 140 + ct2 * 16 + c] = f2bf(fmaxf(acc[j], 0.f));
        }
#pragma unroll
        for (int kc2 = 0; kc2 < 4; ++kc2) {
          bf16x8 a = fragld(hidl + kc2 * 32, 140, lane);
          int kg = fh * 128 + kc2 * 32;
#pragma unroll
          for (int ct = 0; ct < 4; ++ct)
            acc2[ct] = MFMA(a, fragld(W2l + ct * 16 * 512 + kg, 512, lane), acc2[ct]);
        }
      }
      float v[4][4];
#pragma unroll
      for (int ct = 0; ct < 4; ++ct)
#pragma unroll
        for (int j = 0; j < 4; ++j) v[j][ct] = acc2[ct][j] + xf[ct][j];
      ln_write(v, xf, xls, r0, g, c);
    }
    __syncthreads();   // (3) end of layer: xls updated, hid reads done
  }

  // ---- write f32 output (own rows) ----
  float* orow = out + ((size_t)b * LL + r0) * DM;
#pragma unroll
  for (int ct = 0; ct < 4; ++ct)
#pragma unroll
    for (int j = 0; j < 4; ++j)
      orow[(g * 4 + j) * DM + ct * 16 + c] = xf[ct][j];
}

} // namespace

extern "C" void kernel_launch(void* const* d_in, const int* in_sizes, int n_in,
                              void* d_out, int out_size, void* d_ws, size_t ws_size,
                              hipStream_t stream) {
  const int* enc = (const int*)d_in[0];
  const int* deg = (const int*)d_in[1];
  const int* MD  = (const int*)d_in[2];
  const float* semb = (const float*)d_in[3];
  const float* demb = (const float*)d_in[4];
  const float* memb = (const float*)d_in[5];
  const float* Wq = (const float*)d_in[6];
  const float* Wk = (const float*)d_in[7];
  const float* Wv = (const float*)d_in[8];
  const float* Wo = (const float*)d_in[9];
  const float* W1 = (const float*)d_in[10];
  const float* W2 = (const float*)d_in[11];

  // ---- workspace layout (~47 MB) ----
  char* p = (char*)d_ws;
  float*    x    = (float*)p;     p += (size_t)TT * DM * 4;         // embed output, f32
  uint16_t* xb   = (uint16_t*)p;  p += (size_t)TT * DM * 2;         // bf16 shadow
  uint16_t* biasT = (uint16_t*)p; p += (size_t)BB * 4 * LL * LL * 2; // [b][h][r][kk]
  uint16_t* wtqkv = (uint16_t*)p; p += (size_t)NL * 192 * 64 * 2;   // [l][c:192][k:64]
  uint16_t* wto   = (uint16_t*)p; p += (size_t)NL * 64 * 64 * 2;    // [l][c:64][k:64]
  uint16_t* wt1   = (uint16_t*)p; p += (size_t)NL * 512 * 64 * 2;   // [l][c:512][k:64]
  uint16_t* wt2   = (uint16_t*)p; p += (size_t)NL * 64 * 512 * 2;   // [l][c:64][k:512]
  (void)ws_size; (void)in_sizes; (void)n_in; (void)out_size;

  // ---- setup ----
  k_embed<<<TT * DM / 256, 256, 0, stream>>>(enc, deg, semb, demb, x, xb);
  k_trans<<<NL * 64 * 64 / 256, 256, 0, stream>>>(Wq, wtqkv, 64, 64, 192 * 64, 0);
  k_trans<<<NL * 64 * 64 / 256, 256, 0, stream>>>(Wk, wtqkv, 64, 64, 192 * 64, 64);
  k_trans<<<NL * 64 * 64 / 256, 256, 0, stream>>>(Wv, wtqkv, 64, 64, 192 * 64, 128);
  k_trans<<<NL * 64 * 64 / 256, 256, 0, stream>>>(Wo, wto, 64, 64, 64 * 64, 0);
  k_trans<<<NL * 64 * 512 / 256, 256, 0, stream>>>(W1, wt1, 64, 512, 512 * 64, 0);
  k_trans<<<NL * 512 * 64 / 256, 256, 0, stream>>>(W2, wt2, 512, 64, 64 * 512, 0);
  k_bias2<<<BB * LL * LL / 256, 256, 0, stream>>>(MD, memb, enc, biasT);

  // ---- whole network: one 8-wave workgroup per batch element ----
  k_mega<<<BB, 512, 0, stream>>>(x, xb, biasT, wtqkv, wto, wt1, wt2, (float*)d_out);
}